// Round 2
// baseline (206.651 us; speedup 1.0000x reference)
//
#include <hip/hip_runtime.h>

// Erosion = 18x18 separable min-filter, SAME padding (lo=8, hi=9) with +inf,
// applied to x*0.5+0.5. Affine is monotone (and exact under *0.5), so
// f(min) == min(f): filter raw x, apply *0.5+0.5 once at the end.
//
// R2: vectorized both global streams.
//  - Horizontal pass FIRST (contiguous axis): aligned float4 global loads,
//    18-tap min tree in registers, results to LDS H[49][33] (float4).
//  - Vertical pass from LDS (ds_read_b128, stride 132 words == 4 mod 32 ->
//    conflict-free-ish), rolling-min formulation (8 live float4s), direct
//    float4 global stores (no second LDS staging, one barrier total).
// Tile: 128(w) x 32(h) per 256-thread block. LDS 25.9 KB -> 6 blocks/CU.

#define IMG 512

__device__ __forceinline__ float4 f4min(float4 a, float4 b) {
    return make_float4(fminf(a.x, b.x), fminf(a.y, b.y),
                       fminf(a.z, b.z), fminf(a.w, b.w));
}

__global__ __launch_bounds__(256, 4)
void erode_fused_22187801051678(const float* __restrict__ in,
                                float* __restrict__ out) {
    __shared__ float4 H[49][33];  // [haloRow][colGroup], +1 pad group

    const int tid = threadIdx.x;
    const int w0 = blockIdx.x * 128;
    const int h0 = blockIdx.y * 32;
    const size_t plane = (size_t)blockIdx.z * (size_t)(IMG * IMG);

    // ---- phase 1: horizontal 18-tap min. 392 units = 49 rows x 8 chunks
    // (16 outputs each). Chunk loads 36 floats (9 aligned float4s).
    for (int u = tid; u < 392; u += 256) {
        const int chunk = u & 7;
        const int row   = u >> 3;
        const int gh    = h0 - 8 + row;
        const int cbase = w0 + 16 * chunk - 8;  // col of y[0]; multiple of 4

        float y[36];
        if ((unsigned)gh < (unsigned)IMG) {
            const float* rp = in + plane + (size_t)gh * IMG;
#pragma unroll
            for (int g = 0; g < 9; ++g) {
                const int c0 = cbase + 4 * g;  // 4-aligned: group fully in or out
                float4 v;
                if ((unsigned)c0 < (unsigned)IMG)
                    v = *reinterpret_cast<const float4*>(rp + c0);
                else
                    v = make_float4(__builtin_inff(), __builtin_inff(),
                                    __builtin_inff(), __builtin_inff());
                y[4 * g + 0] = v.x; y[4 * g + 1] = v.y;
                y[4 * g + 2] = v.z; y[4 * g + 3] = v.w;
            }
        } else {
#pragma unroll
            for (int i = 0; i < 36; ++i) y[i] = __builtin_inff();
        }

        // 16 windowed mins (window 18) from y[0..32] via pair/quad tree
        float p[32];
#pragma unroll
        for (int i = 0; i < 32; ++i) p[i] = fminf(y[i], y[i + 1]);
        float q[30];
#pragma unroll
        for (int i = 0; i < 30; ++i) q[i] = fminf(p[i], p[i + 2]);
        float o[16];
#pragma unroll
        for (int j = 0; j < 16; ++j) {
            float m = fminf(fminf(q[j], q[j + 4]), fminf(q[j + 8], q[j + 12]));
            o[j] = fminf(m, p[j + 16]);
        }
#pragma unroll
        for (int jj = 0; jj < 4; ++jj)
            H[row][4 * chunk + jj] =
                make_float4(o[4 * jj], o[4 * jj + 1], o[4 * jj + 2], o[4 * jj + 3]);
    }
    __syncthreads();

    // ---- phase 2: vertical 18-tap min + affine + direct float4 store.
    // 256 units = 32 float4-columns x 8 segs of 4 output rows.
    {
        const int c   = tid & 31;
        const int seg = tid >> 5;
        const int rb  = seg * 4;

        float4 x0 = H[rb + 0][c];
        float4 x1 = H[rb + 1][c];
        float4 x2 = H[rb + 2][c];
        float4 cm = H[rb + 3][c];           // rolling min of rows rb+3..rb+17
#pragma unroll
        for (int k = 4; k <= 17; ++k) cm = f4min(cm, H[rb + k][c]);
        float4 x18 = H[rb + 18][c];
        float4 x19 = H[rb + 19][c];
        float4 x20 = H[rb + 20][c];

        float4 o0 = f4min(f4min(x0, x1), f4min(x2, cm));
        float4 o1 = f4min(f4min(x1, x2), f4min(cm, x18));
        float4 o2 = f4min(x2, f4min(cm, f4min(x18, x19)));
        float4 o3 = f4min(f4min(cm, x18), f4min(x19, x20));

        float* op = out + plane + (size_t)(h0 + rb) * IMG + (w0 + 4 * c);
#define AFF4(v) make_float4(v.x * 0.5f + 0.5f, v.y * 0.5f + 0.5f, \
                            v.z * 0.5f + 0.5f, v.w * 0.5f + 0.5f)
        *reinterpret_cast<float4*>(op)            = AFF4(o0);
        *reinterpret_cast<float4*>(op + IMG)      = AFF4(o1);
        *reinterpret_cast<float4*>(op + 2 * IMG)  = AFF4(o2);
        *reinterpret_cast<float4*>(op + 3 * IMG)  = AFF4(o3);
#undef AFF4
    }
}

extern "C" void kernel_launch(void* const* d_in, const int* in_sizes, int n_in,
                              void* d_out, int out_size, void* d_ws, size_t ws_size,
                              hipStream_t stream) {
    const float* x = (const float*)d_in[0];
    float* out = (float*)d_out;
    const int planes = in_sizes[0] / (IMG * IMG);  // 96 for (32,3,512,512)
    dim3 grid(IMG / 128, IMG / 32, planes);
    erode_fused_22187801051678<<<grid, dim3(256), 0, stream>>>(x, out);
}

// Round 3
// 194.695 us; speedup vs baseline: 1.0614x; 1.0614x over previous
//
#include <hip/hip_runtime.h>

// Erosion = 18x18 separable min-filter, SAME padding (lo=8, hi=9) with +inf,
// applied to x*0.5+0.5. Affine is monotone & exact under *0.5+0.5, so we
// min-filter raw x and apply the affine once at the end (bitwise identical).
//
// R3 = R1 structure, occupancy-fixed:
//  - phase 1: vertical 18-tap min (coalesced column loads -> reg tree -> LDS
//    B[32][145]; stride 145 == 17 mod 32, odd -> conflict-free both phases)
//  - phase 2: horizontal 18-tap min from LDS + affine + DIRECT float4 stores
//    (each thread's 16 outputs are exactly one 64B line -> L2 write-combines;
//    no Bo staging, no second barrier)
//  - LDS 18.5 KB (was 35.3) -> 8 blocks/CU; __launch_bounds__(256,8) -> 32
//    waves/CU (max occupancy) to hide global-load latency.

#define IMG 512
#define RLO 8  // pad_low for k=18 SAME; window for output i is [i-8, i+9]

__global__ __launch_bounds__(256, 8)
void erode_fused_22187801051678(const float* __restrict__ in,
                                float* __restrict__ out) {
    __shared__ float B[32][145];  // vertical-min results

    const int tid = threadIdx.x;
    const int w0 = blockIdx.x * 128;
    const int h0 = blockIdx.y * 32;
    const size_t plane = (size_t)blockIdx.z * (size_t)(IMG * IMG);

    // ---- phase 1: vertical min. 290 units = 145 cols x 2 segs (16 out rows)
    for (int u = tid; u < 290; u += 256) {
        int col, seg;
        if (u < 145) { col = u;       seg = 0; }
        else         { col = u - 145; seg = 1; }
        const int gw  = w0 - RLO + col;           // lanes -> consecutive cols
        const bool wok = (unsigned)gw < (unsigned)IMG;
        const int ghb = h0 - RLO + seg * 16;

        float x[33];
#pragma unroll
        for (int i = 0; i < 33; ++i) {
            const int gh = ghb + i;
            float v = __builtin_inff();
            if (wok && (unsigned)gh < (unsigned)IMG)
                v = in[plane + (size_t)gh * IMG + gw];
            x[i] = v;
        }
        // 16 windowed mins (window 18) from x[0..32] via pair/quad tree
        float p[32];
#pragma unroll
        for (int i = 0; i < 32; ++i) p[i] = fminf(x[i], x[i + 1]);
        float q[30];
#pragma unroll
        for (int i = 0; i < 30; ++i) q[i] = fminf(p[i], p[i + 2]);
#pragma unroll
        for (int j = 0; j < 16; ++j) {
            float m = fminf(fminf(q[j], q[j + 4]), fminf(q[j + 8], q[j + 12]));
            B[seg * 16 + j][col] = fminf(m, p[j + 16]);
        }
    }
    __syncthreads();

    // ---- phase 2: horizontal min + affine + direct stores.
    // 256 units: row r = tid&31 (stride-145 LDS reads, conflict-free),
    // 16-wide chunk c8 = tid>>5. 16 outputs = exactly one 64B line.
    {
        const int r  = tid & 31;
        const int c8 = tid >> 5;
        float y[33];
#pragma unroll
        for (int i = 0; i < 33; ++i) y[i] = B[r][c8 * 16 + i];
        float p[32];
#pragma unroll
        for (int i = 0; i < 32; ++i) p[i] = fminf(y[i], y[i + 1]);
        float q[30];
#pragma unroll
        for (int i = 0; i < 30; ++i) q[i] = fminf(p[i], p[i + 2]);
        float o[16];
#pragma unroll
        for (int j = 0; j < 16; ++j) {
            float m = fminf(fminf(q[j], q[j + 4]), fminf(q[j + 8], q[j + 12]));
            o[j] = fminf(m, p[j + 16]) * 0.5f + 0.5f;
        }
        float* op = out + plane + (size_t)(h0 + r) * IMG + (w0 + c8 * 16);
#pragma unroll
        for (int jj = 0; jj < 4; ++jj)
            *reinterpret_cast<float4*>(op + 4 * jj) =
                make_float4(o[4 * jj], o[4 * jj + 1], o[4 * jj + 2], o[4 * jj + 3]);
    }
}

extern "C" void kernel_launch(void* const* d_in, const int* in_sizes, int n_in,
                              void* d_out, int out_size, void* d_ws, size_t ws_size,
                              hipStream_t stream) {
    const float* x = (const float*)d_in[0];
    float* out = (float*)d_out;
    const int planes = in_sizes[0] / (IMG * IMG);  // 96 for (32,3,512,512)
    dim3 grid(IMG / 128, IMG / 32, planes);
    erode_fused_22187801051678<<<grid, dim3(256), 0, stream>>>(x, out);
}